// Round 7
// baseline (343.958 us; speedup 1.0000x reference)
//
#include <hip/hip_runtime.h>
#include <hip/hip_bf16.h>

// Round 7: (1) Q gemm eliminated via Wfold = WeffT . Wq^T fold (8.6 GF vs
// 17.2 GF + 64 MB Q traffic); (2) ctx k-split x4 across blocks (4 blocks/CU,
// partials summed in weff); (3) gemm LDS row stride reverted to 32 shorts
// (round-4 layout: half the bank conflicts of the 40-short pad).
//
// Pipeline:
//   Xt[b][n][c]     = x transposed+converted            @0        (32 MB)
//   WT=[WkT|WvT]    [hd][c]                             @117440512 (1 MB)
//   Wqb[c'][hd]     = cast(Wq)                          @118489088 (0.5 MB)
//   KV[b][hd2][n]   = gemm(A=[WkT;WvT], B=Xt)           @33554432 (64 MB)
//   softmax over n on K rows (in place)
//   ctxp[s][bh][d][v] = partial MFMA K.V^T (k-split 4)  @100663296 (16 MB f32)
//   WeffT[b][c][hd] = sum_s,v ctxp * Wp                 @33554432 (KV dead, 16 MB)
//   Wfold[b][c][c'] = gemm(A=WeffT, B=Wqb)              @50331648 (16 MB)
//   out[b][c][n]    = gemm(A=Wfold, B=Xt) + bp          -> d_out

__device__ __forceinline__ float bf2f(unsigned short u) {
    union { unsigned int i; float f; } x;
    x.i = ((unsigned int)u) << 16;
    return x.f;
}
__device__ __forceinline__ unsigned short f2bf(float f) {
    unsigned int u = __float_as_uint(f);
    unsigned int lsb = (u >> 16) & 1u;
    u += 0x7fffu + lsb;             // RNE
    return (unsigned short)(u >> 16);
}
__device__ __forceinline__ float waveReduceMax(float v) {
    #pragma unroll
    for (int off = 32; off > 0; off >>= 1) v = fmaxf(v, __shfl_xor(v, off, 64));
    return v;
}
__device__ __forceinline__ float waveReduceSum(float v) {
    #pragma unroll
    for (int off = 32; off > 0; off >>= 1) v += __shfl_xor(v, off, 64);
    return v;
}

typedef __bf16 bf16x8 __attribute__((ext_vector_type(8)));
typedef float  f32x4  __attribute__((ext_vector_type(4)));

// flag: 1 = inputs are bf16, 0 = fp32 (detected at runtime)
__global__ void detect_dtype(const unsigned short* __restrict__ x, int* __restrict__ flag)
{
    int t = threadIdx.x;                      // 64 threads
    unsigned short u = x[2 * t];
    int e = (u >> 7) & 0xFF;
    int sane = (e >= 113 && e <= 142) ? 1 : 0;
    #pragma unroll
    for (int off = 32; off > 0; off >>= 1) sane += __shfl_xor(sane, off, 64);
    if (t == 0) *flag = (sane >= 32) ? 1 : 0;
}

// x [b][512 c][1024 n] (flag dtype) -> Xt [b][n][c] bf16 (row stride 512)
__global__ __launch_bounds__(256) void transpose_x(
    const void* __restrict__ in, unsigned short* __restrict__ out,
    const int* __restrict__ flag)
{
    const int fl = *flag;
    const int b  = blockIdx.z;
    const int c0 = blockIdx.x * 64;   // over n (1024)
    const int r0 = blockIdx.y * 64;   // over c (512)
    __shared__ unsigned short Ts[64][68];
    const int t   = threadIdx.x;
    const int tr  = t >> 4;
    const int tc4 = (t & 15) * 4;
    #pragma unroll
    for (int rr = 0; rr < 4; ++rr) {
        int rl = rr * 16 + tr;
        long off = (long)b * 524288 + (long)(r0 + rl) * 1024 + c0 + tc4;
        unsigned short v[4];
        if (fl) {
            ushort4 u = *(const ushort4*)((const unsigned short*)in + off);
            v[0] = u.x; v[1] = u.y; v[2] = u.z; v[3] = u.w;
        } else {
            float4 u = *(const float4*)((const float*)in + off);
            v[0] = f2bf(u.x); v[1] = f2bf(u.y); v[2] = f2bf(u.z); v[3] = f2bf(u.w);
        }
        #pragma unroll
        for (int q = 0; q < 4; ++q) Ts[tc4 + q][rl] = v[q];
    }
    __syncthreads();
    #pragma unroll
    for (int rr = 0; rr < 4; ++rr) {
        int cl = rr * 16 + tr;
        ushort4 o = *(const ushort4*)&Ts[cl][tc4];
        *(ushort4*)(out + (long)b * 524288 + (long)(c0 + cl) * 512 + r0 + tc4) = o;
    }
}

// W [512 c][512 hd] -> WT + z*262144 [512 hd][512 c], z=0:Wk, z=1:Wv
__global__ __launch_bounds__(256) void transpose_w2(
    const void* __restrict__ w0, const void* __restrict__ w1,
    unsigned short* __restrict__ out, const int* __restrict__ flag)
{
    const int fl = *flag;
    const int z  = blockIdx.z;
    const void* in = (z == 0) ? w0 : w1;
    unsigned short* op = out + (long)z * 262144;
    const int c0 = blockIdx.x * 64;
    const int r0 = blockIdx.y * 64;
    __shared__ unsigned short Ts[64][68];
    const int t   = threadIdx.x;
    const int tr  = t >> 4;
    const int tc4 = (t & 15) * 4;
    #pragma unroll
    for (int rr = 0; rr < 4; ++rr) {
        int rl = rr * 16 + tr;
        long off = (long)(r0 + rl) * 512 + c0 + tc4;
        unsigned short v[4];
        if (fl) {
            ushort4 u = *(const ushort4*)((const unsigned short*)in + off);
            v[0] = u.x; v[1] = u.y; v[2] = u.z; v[3] = u.w;
        } else {
            float4 u = *(const float4*)((const float*)in + off);
            v[0] = f2bf(u.x); v[1] = f2bf(u.y); v[2] = f2bf(u.z); v[3] = f2bf(u.w);
        }
        #pragma unroll
        for (int q = 0; q < 4; ++q) Ts[tc4 + q][rl] = v[q];
    }
    __syncthreads();
    #pragma unroll
    for (int rr = 0; rr < 4; ++rr) {
        int cl = rr * 16 + tr;
        ushort4 o = *(const ushort4*)&Ts[cl][tc4];
        *(ushort4*)(op + (long)(c0 + cl) * 512 + r0 + tc4) = o;
    }
}

// Wq [512][512] flag dtype -> Wqb bf16, same layout. 256 blocks x 256 thr x 4
__global__ __launch_bounds__(256) void cast_wq(
    const void* __restrict__ in, unsigned short* __restrict__ out,
    const int* __restrict__ flag)
{
    const int fl = *flag;
    const long idx = ((long)blockIdx.x * 256 + threadIdx.x) * 4;
    if (fl) {
        *(ushort4*)(out + idx) = *(const ushort4*)((const unsigned short*)in + idx);
    } else {
        float4 u = *(const float4*)((const float*)in + idx);
        ushort4 o;
        o.x = f2bf(u.x); o.y = f2bf(u.y); o.z = f2bf(u.z); o.w = f2bf(u.w);
        *(ushort4*)(out + idx) = o;
    }
}

// C = A . B^T : A [M][K] bf16 k-contig, B [N][K] bf16 k-contig, fp32 acc.
// 128x128 block tile, 4 waves of 64x64, BK=32, register-prefetch pipeline.
// mode 0: C bf16 row-major [M][N]
// mode 2: C [M][N] + bias[m]; C/bias dtype per flag (1=bf16, 0=fp32)
__global__ __launch_bounds__(256) void gemm_bt_mfma(
    const unsigned short* __restrict__ A, long a_bstride,
    const unsigned short* __restrict__ Bm, long b_bstride,
    void* __restrict__ C, long c_bstride,
    const void* __restrict__ bias,
    int M, int N, int K, int mode,
    const int* __restrict__ flag)
{
    const int b  = blockIdx.z;
    const int n0 = blockIdx.x * 128;
    const int m0 = blockIdx.y * 128;
    const unsigned short* Ab = A  + (long)b * a_bstride;
    const unsigned short* Bb = Bm + (long)b * b_bstride;

    __shared__ unsigned short As[128 * 32];   // 64 B rows (round-4 layout)
    __shared__ unsigned short Bs[128 * 32];

    const int t    = threadIdx.x;
    const int w    = t >> 6;
    const int lane = t & 63;
    const int wm   = (w & 1) * 64;
    const int wn   = (w >> 1) * 64;
    const int fm   = lane & 15;
    const int kg   = lane >> 4;

    const int srow = t >> 2;        // staging row 0..63 (plus +64)
    const int scol = (t & 3) * 8;   // staging col (elements)

    f32x4 acc[4][4] = {};

    // prefetch k0 = 0
    uint4 a0 = *(const uint4*)(Ab + (long)(m0 + srow)      * K + scol);
    uint4 a1 = *(const uint4*)(Ab + (long)(m0 + srow + 64) * K + scol);
    uint4 b0 = *(const uint4*)(Bb + (long)(n0 + srow)      * K + scol);
    uint4 b1 = *(const uint4*)(Bb + (long)(n0 + srow + 64) * K + scol);

    for (int k0 = 0; k0 < K; k0 += 32) {
        __syncthreads();            // prev iter frag reads done
        *(uint4*)&As[srow * 32 + scol]        = a0;
        *(uint4*)&As[(srow + 64) * 32 + scol] = a1;
        *(uint4*)&Bs[srow * 32 + scol]        = b0;
        *(uint4*)&Bs[(srow + 64) * 32 + scol] = b1;
        __syncthreads();

        if (k0 + 32 < K) {          // prefetch next tile under MFMA
            const int kn = k0 + 32;
            a0 = *(const uint4*)(Ab + (long)(m0 + srow)      * K + kn + scol);
            a1 = *(const uint4*)(Ab + (long)(m0 + srow + 64) * K + kn + scol);
            b0 = *(const uint4*)(Bb + (long)(n0 + srow)      * K + kn + scol);
            b1 = *(const uint4*)(Bb + (long)(n0 + srow + 64) * K + kn + scol);
        }

        bf16x8 af[4], bf[4];
        #pragma unroll
        for (int i = 0; i < 4; ++i)
            af[i] = *(const bf16x8*)&As[(wm + i * 16 + fm) * 32 + kg * 8];
        #pragma unroll
        for (int j = 0; j < 4; ++j)
            bf[j] = *(const bf16x8*)&Bs[(wn + j * 16 + fm) * 32 + kg * 8];
        #pragma unroll
        for (int i = 0; i < 4; ++i)
            #pragma unroll
            for (int j = 0; j < 4; ++j)
                acc[i][j] = __builtin_amdgcn_mfma_f32_16x16x32_bf16(
                    af[i], bf[j], acc[i][j], 0, 0, 0);
    }

    // D layout: col(n) = lane&15, row(m) = (lane>>4)*4 + reg
    const int fl = *flag;
    const long cb = (long)b * c_bstride;
    #pragma unroll
    for (int i = 0; i < 4; ++i) {
        #pragma unroll
        for (int j = 0; j < 4; ++j) {
            const int n = n0 + wn + j * 16 + fm;
            #pragma unroll
            for (int r = 0; r < 4; ++r) {
                const int m = m0 + wm + i * 16 + kg * 4 + r;
                const float val = acc[i][j][r];
                if (mode == 0) {
                    ((unsigned short*)C)[cb + (long)m * N + n] = f2bf(val);
                } else {
                    float bv = 0.f;
                    if (bias) bv = fl ? bf2f(((const unsigned short*)bias)[m])
                                      : ((const float*)bias)[m];
                    const long off = cb + (long)m * N + n;
                    if (fl) ((unsigned short*)C)[off] = f2bf(val + bv);
                    else    ((float*)C)[off] = val + bv;
                }
            }
        }
    }
}

// In-place row softmax over n on K rows of KV: row = b*512 + r, r < 512
__global__ __launch_bounds__(256) void softmax_rows(unsigned short* __restrict__ KV)
{
    const long row = blockIdx.x;
    unsigned short* p = KV + ((row >> 9) << 20) + ((row & 511) << 10);
    const int t = threadIdx.x;

    ushort4 raw = *(const ushort4*)(p + t * 4);
    float f[4] = {bf2f(raw.x), bf2f(raw.y), bf2f(raw.z), bf2f(raw.w)};

    float m = fmaxf(fmaxf(f[0], f[1]), fmaxf(f[2], f[3]));
    m = waveReduceMax(m);
    __shared__ float redm[4], reds[4];
    if ((t & 63) == 0) redm[t >> 6] = m;
    __syncthreads();
    m = fmaxf(fmaxf(redm[0], redm[1]), fmaxf(redm[2], redm[3]));

    float e[4], s = 0.f;
    #pragma unroll
    for (int i = 0; i < 4; ++i) { e[i] = expf(f[i] - m); s += e[i]; }
    s = waveReduceSum(s);
    if ((t & 63) == 0) reds[t >> 6] = s;
    __syncthreads();
    s = reds[0] + reds[1] + reds[2] + reds[3];
    const float inv = 1.0f / s;

    ushort4 o;
    o.x = f2bf(e[0] * inv); o.y = f2bf(e[1] * inv);
    o.z = f2bf(e[2] * inv); o.w = f2bf(e[3] * inv);
    *(ushort4*)(p + t * 4) = o;
}

// ctxp[s][bh][d][v] = sum_{n in slice s} K[bh,d,n] * V[bh,v,n]
// grid (256, 4): 1024 blocks (4 blocks/CU). Block s covers k in [s*256,+256);
// 4 waves split that 4-ways (64 each), LDS-reduced, partial written fp32.
__global__ __launch_bounds__(256) void ctx_mfma(
    const unsigned short* __restrict__ KV, float* __restrict__ ctxp)
{
    const int bh = blockIdx.x;
    const int s  = blockIdx.y;
    const unsigned short* Kb = KV + ((long)(bh >> 3) << 20) + (long)(bh & 7) * 65536;
    const unsigned short* Vb = Kb + 524288;   // V half of KV

    const int t    = threadIdx.x;
    const int w    = t >> 6;
    const int lane = t & 63;
    const int fm   = lane & 15;
    const int kg   = lane >> 4;

    f32x4 acc[4][4] = {};

    #pragma unroll
    for (int c = 0; c < 2; ++c) {
        const int k0 = s * 256 + w * 64 + c * 32;
        bf16x8 af[4], bf[4];
        #pragma unroll
        for (int i = 0; i < 4; ++i)
            af[i] = *(const bf16x8*)(Kb + (long)(i * 16 + fm) * 1024 + k0 + kg * 8);
        #pragma unroll
        for (int j = 0; j < 4; ++j)
            bf[j] = *(const bf16x8*)(Vb + (long)(j * 16 + fm) * 1024 + k0 + kg * 8);
        #pragma unroll
        for (int i = 0; i < 4; ++i)
            #pragma unroll
            for (int j = 0; j < 4; ++j)
                acc[i][j] = __builtin_amdgcn_mfma_f32_16x16x32_bf16(
                    af[i], bf[j], acc[i][j], 0, 0, 0);
    }

    __shared__ float red[64][65];
    for (int ph = 0; ph < 4; ++ph) {
        if (w == ph) {
            #pragma unroll
            for (int i = 0; i < 4; ++i)
                #pragma unroll
                for (int j = 0; j < 4; ++j)
                    #pragma unroll
                    for (int r = 0; r < 4; ++r) {
                        const int m = i * 16 + kg * 4 + r;
                        const int n = j * 16 + fm;
                        if (ph == 0) red[m][n]  = acc[i][j][r];
                        else         red[m][n] += acc[i][j][r];
                    }
        }
        __syncthreads();
    }
    float* cp = ctxp + (long)s * 1048576 + (long)bh * 4096;
    for (int i = t; i < 4096; i += 256) cp[i] = red[i >> 6][i & 63];
}

// WeffT[b][c][h*64+d] = sum_v (sum_s ctxp[s][b,h,d,v]) * Wp[h*64+v][c]
__global__ __launch_bounds__(256) void weff_kernel(
    const float* __restrict__ ctxp,         // [4][256][64][64] fp32 partials
    const void* __restrict__ Wp,            // [512,512] flag dtype, c-contig
    unsigned short* __restrict__ WeffT,     // [B,512,512] bf16, hd-contig
    const int* __restrict__ flag)
{
    const int fl = *flag;
    const int c0 = blockIdx.x * 64;
    const int h  = blockIdx.y;
    const int b  = blockIdx.z;

    __shared__ float Cs[64][65];   // [d][v]
    __shared__ float Ws[64][68];   // [v][c]

    const int t = threadIdx.x;
    const int tx = t & 15, ty = t >> 4;

    const float* cb = ctxp + ((long)b * 8 + h) * 4096;
    for (int i = t; i < 4096; i += 256)
        Cs[i >> 6][i & 63] = cb[i] + cb[i + 1048576] + cb[i + 2097152] + cb[i + 3145728];
    for (int i = t; i < 4096; i += 256) {
        int v = i >> 6, c = i & 63;
        long idx = (long)(h * 64 + v) * 512 + c0 + c;
        Ws[v][c] = fl ? bf2f(((const unsigned short*)Wp)[idx])
                      : ((const float*)Wp)[idx];
    }
    __syncthreads();

    float acc[4][4];
    #pragma unroll
    for (int i = 0; i < 4; ++i)
        #pragma unroll
        for (int j = 0; j < 4; ++j) acc[i][j] = 0.f;

    #pragma unroll
    for (int v = 0; v < 64; ++v) {
        float a[4], d[4];
        #pragma unroll
        for (int i = 0; i < 4; ++i) a[i] = Ws[v][ty * 4 + i];   // over c
        #pragma unroll
        for (int j = 0; j < 4; ++j) d[j] = Cs[tx * 4 + j][v];   // over d
        #pragma unroll
        for (int i = 0; i < 4; ++i)
            #pragma unroll
            for (int j = 0; j < 4; ++j) acc[i][j] += a[i] * d[j];
    }
    #pragma unroll
    for (int i = 0; i < 4; ++i) {
        ushort4 o;
        o.x = f2bf(acc[i][0]); o.y = f2bf(acc[i][1]);
        o.z = f2bf(acc[i][2]); o.w = f2bf(acc[i][3]);
        *(ushort4*)&WeffT[((long)b * 512 + c0 + ty * 4 + i) * 512 + h * 64 + tx * 4] = o;
    }
}

extern "C" void kernel_launch(void* const* d_in, const int* in_sizes, int n_in,
                              void* d_out, int out_size, void* d_ws, size_t ws_size,
                              hipStream_t stream) {
    const void* x  = d_in[0];
    const void* Wq = d_in[1];
    const void* Wk = d_in[2];
    const void* Wv = d_in[3];
    const void* Wp = d_in[4];
    const void* bp = d_in[5];

    char* ws = (char*)d_ws;
    unsigned short* Xt    = (unsigned short*)(ws);                // 32 MB [b][n][c]
    unsigned short* KV    = (unsigned short*)(ws + 33554432ll);   // 64 MB [b][1024][1024]
    unsigned short* WeffT = (unsigned short*)(ws + 33554432ll);   // 16 MB (KV dead)
    unsigned short* Wfold = (unsigned short*)(ws + 50331648ll);   // 16 MB (KV dead)
    float*          ctxp  = (float*)(ws + 100663296ll);           // 16 MB fp32 x4
    unsigned short* WT    = (unsigned short*)(ws + 117440512ll);  //  1 MB [WkT|WvT]
    unsigned short* Wqb   = (unsigned short*)(ws + 118489088ll);  // 0.5 MB
    int*            flag  = (int*)(ws + 119013376ll);

    detect_dtype<<<dim3(1), dim3(64), 0, stream>>>((const unsigned short*)x, flag);

    transpose_x<<<dim3(16, 8, 32), 256, 0, stream>>>(x, Xt, flag);
    transpose_w2<<<dim3(8, 8, 2), 256, 0, stream>>>(Wk, Wv, WT, flag);
    cast_wq<<<dim3(256), 256, 0, stream>>>(Wq, Wqb, flag);

    const long XB = 1024ll * 512;
    // KV[b][hd2][n] = [WkT;WvT] . Xt^T   (M=1024, N=1024, K=512)
    gemm_bt_mfma<<<dim3(8, 8, 32), 256, 0, stream>>>(
        WT, 0, Xt, XB, KV, 1048576ll, nullptr, 1024, 1024, 512, 0, flag);

    softmax_rows<<<dim3(16384), 256, 0, stream>>>(KV);
    ctx_mfma<<<dim3(256, 4), 256, 0, stream>>>(KV, ctxp);
    weff_kernel<<<dim3(8, 8, 32), 256, 0, stream>>>(ctxp, Wp, WeffT, flag);

    // Wfold[b][c][c'] = WeffT . Wqb^T   (M=512, N=512, K=512)
    gemm_bt_mfma<<<dim3(4, 4, 32), 256, 0, stream>>>(
        WeffT, 262144ll, Wqb, 0, Wfold, 262144ll, nullptr, 512, 512, 512, 0, flag);

    // out[b][c][n] = Wfold . Xt^T + bp   (M=512, N=1024, K=512)
    gemm_bt_mfma<<<dim3(8, 4, 32), 256, 0, stream>>>(
        Wfold, 262144ll, Xt, XB, d_out, 524288ll, bp, 512, 1024, 512, 2, flag);
}